// Round 1
// baseline (6036.319 us; speedup 1.0000x reference)
//
#include <hip/hip_runtime.h>
#include <math.h>

// Greedy LSTM decoder, MI355X (gfx950).
// B=128, E=512, H=1024, V=32000, T=48 (47 compute steps).
//
// Accuracy strategy:
//  - gates: bf16 3-way-split MFMA, 6 passes (error ~1e-6 rel, fp32-acc limited)
//  - logits: bf16 hi*hi single pass (abs err ~4e-3 << 1.57e-2 threshold)
//  - argmax: top-8 candidates from approx logits, re-scored with fp64 dots
//    against fp32 h and fp32 w_out -> fp64-exact token selection.

typedef unsigned short u16;
typedef unsigned int u32;
typedef __bf16 bf16x8 __attribute__((ext_vector_type(8)));
typedef float f32x4 __attribute__((ext_vector_type(4)));

#define B_ 128
#define E_ 512
#define H_ 1024
#define V_ 32000
#define G4 4096
#define KX 1536  // E_ + H_

__device__ __forceinline__ u16 f2bf(float f){
  u32 u = __float_as_uint(f);
  u32 r = (u + 0x7FFFu + ((u >> 16) & 1u)) >> 16;  // RNE
  return (u16)r;
}
__device__ __forceinline__ float bf2f(u16 s){ return __uint_as_float(((u32)s) << 16); }
__device__ __forceinline__ void split3(float x, u16 &a, u16 &b, u16 &c){
  a = f2bf(x); float r1 = x - bf2f(a);
  b = f2bf(r1); float r2 = r1 - bf2f(b);
  c = f2bf(r2);
}
__device__ __forceinline__ bf16x8 ldb8(const u16* p){ return *reinterpret_cast<const bf16x8*>(p); }
__device__ __forceinline__ f32x4 mf(bf16x8 a, bf16x8 b, f32x4 c){
  return __builtin_amdgcn_mfma_f32_16x16x32_bf16(a, b, c, 0, 0, 0);
}

// ---------------- precompute kernels ----------------

// zero out[t=0] slice: 4000*256 float4 == 128*32000 floats
__global__ void k_zero(float* __restrict__ p){
  const int i = blockIdx.x * 256 + threadIdx.x;
  reinterpret_cast<float4*>(p)[i] = make_float4(0.f, 0.f, 0.f, 0.f);
}

// w_out fp32 [V][H] -> bf16 hi [V][H]
__global__ void k_wout(const float* __restrict__ w, u16* __restrict__ wo){
  const int i = blockIdx.x * 256 + threadIdx.x;  // 32000 blocks
  float4 v = reinterpret_cast<const float4*>(w)[i];
  ushort4 o;
  o.x = f2bf(v.x); o.y = f2bf(v.y); o.z = f2bf(v.z); o.w = f2bf(v.w);
  reinterpret_cast<ushort4*>(wo)[i] = o;
}

// W_cat[n][k] = [w_ih | w_hh], 3-way bf16 split.  grid (6, 4096)
__global__ void k_wc(const float* __restrict__ wih, const float* __restrict__ whh,
                     u16* __restrict__ ch, u16* __restrict__ cm, u16* __restrict__ cl){
  const int k = blockIdx.x * 256 + threadIdx.x;
  const int n = blockIdx.y;
  float v = (k < E_) ? wih[(size_t)n * E_ + k] : whh[(size_t)n * H_ + (k - E_)];
  u16 a, b, c; split3(v, a, b, c);
  const size_t o = (size_t)n * KX + k;
  ch[o] = a; cm[o] = b; cl[o] = c;
}

// xh(t=1) = [embedding[sos] | encoder_h], split.  grid (6, 128)
__global__ void k_xh0(const float* __restrict__ emb, const float* __restrict__ ench,
                      const int* __restrict__ sos,
                      u16* __restrict__ xh, u16* __restrict__ xm, u16* __restrict__ xl){
  const int k = blockIdx.x * 256 + threadIdx.x;
  const int m = blockIdx.y;
  float v = (k < E_) ? emb[(size_t)sos[0] * E_ + k] : ench[(size_t)m * H_ + (k - E_)];
  u16 a, b, c; split3(v, a, b, c);
  const int o = m * KX + k;
  xh[o] = a; xm[o] = b; xl[o] = c;
}

// c init = encoder_c.  grid 512
__global__ void k_c0(const float* __restrict__ src, float* __restrict__ dst){
  const int i = blockIdx.x * 256 + threadIdx.x;
  dst[i] = src[i];
}

// ---------------- per-step kernels ----------------

// gates GEMM: [128 x 1536] * W_cat^T -> partials [4][128][4096], 6-pass bf16 split.
// grid 512 x 64thr: bid = {w:2 | nb:6 | mb:1}; each block = 1 wave, K-quarter w.
__global__ __launch_bounds__(64) void k_gates(
    const u16* __restrict__ xh_h, const u16* __restrict__ xh_m, const u16* __restrict__ xh_l,
    const u16* __restrict__ wc_h, const u16* __restrict__ wc_m, const u16* __restrict__ wc_l,
    float* __restrict__ part){
  const int L = threadIdx.x;
  const u32 bid = blockIdx.x;
  const int w  = bid & 3;
  const int nb = (bid >> 2) & 63;
  const int mb = (int)(bid >> 8);
  const int l15 = L & 15, q = L >> 4;
  const int kb = w * 384 + q * 8;

  const u16* pa[3] = { xh_h, xh_m, xh_l };
  const u16* pb[3] = { wc_h, wc_m, wc_l };

  f32x4 acc[4][4];
  const f32x4 z4 = {0.f, 0.f, 0.f, 0.f};
#pragma unroll
  for (int i = 0; i < 4; ++i)
#pragma unroll
    for (int g = 0; g < 4; ++g) acc[i][g] = z4;

  const int arow0 = mb * 64 + l15;     // batch row (+ i*16)
  const int brow0 = nb * 16 + l15;     // unit col (+ g*1024)

#pragma unroll 1
  for (int it = 0; it < 6; ++it){
#pragma unroll
    for (int kc = 0; kc < 2; ++kc){
      const int ko = kb + it * 64 + kc * 32;
      bf16x8 af[4][3], bfr[4][3];
#pragma unroll
      for (int i = 0; i < 4; ++i)
#pragma unroll
        for (int s = 0; s < 3; ++s)
          af[i][s] = ldb8(pa[s] + (size_t)(arow0 + i * 16) * KX + ko);
#pragma unroll
      for (int g = 0; g < 4; ++g)
#pragma unroll
        for (int s = 0; s < 3; ++s)
          bfr[g][s] = ldb8(pb[s] + (size_t)(g * 1024 + brow0) * KX + ko);
#pragma unroll
      for (int i = 0; i < 4; ++i)
#pragma unroll
        for (int g = 0; g < 4; ++g){
          f32x4 a_ = acc[i][g];
          a_ = mf(af[i][0], bfr[g][0], a_);  // hi*hi
          a_ = mf(af[i][0], bfr[g][1], a_);  // hi*mid
          a_ = mf(af[i][1], bfr[g][0], a_);  // mid*hi
          a_ = mf(af[i][0], bfr[g][2], a_);  // hi*lo
          a_ = mf(af[i][1], bfr[g][1], a_);  // mid*mid
          a_ = mf(af[i][2], bfr[g][0], a_);  // lo*hi
          acc[i][g] = a_;
        }
    }
  }
#pragma unroll
  for (int i = 0; i < 4; ++i)
#pragma unroll
    for (int g = 0; g < 4; ++g)
#pragma unroll
      for (int r = 0; r < 4; ++r){
        const int row = mb * 64 + i * 16 + q * 4 + r;
        const int col = g * 1024 + nb * 16 + l15;
        part[(size_t)(w * B_ + row) * G4 + col] = acc[i][g][r];
      }
}

// LSTM cell: sum 4 K-partials + bias, activations, update c/h, write h splits.
__global__ __launch_bounds__(256) void k_cell(
    const float* __restrict__ part, const float* __restrict__ bih, const float* __restrict__ bhh,
    float* __restrict__ c_f, float* __restrict__ h_f,
    u16* __restrict__ xh_h, u16* __restrict__ xh_m, u16* __restrict__ xh_l){
  const int idx = blockIdx.x * 256 + threadIdx.x;  // 512 blocks
  const int m = idx >> 10, u = idx & 1023;
  float gi = bih[u] + bhh[u];
  float gf = bih[1024 + u] + bhh[1024 + u];
  float gg = bih[2048 + u] + bhh[2048 + u];
  float go = bih[3072 + u] + bhh[3072 + u];
#pragma unroll
  for (int s = 0; s < 4; ++s){
    const float* p = part + (size_t)(s * B_ + m) * G4 + u;
    gi += p[0]; gf += p[1024]; gg += p[2048]; go += p[3072];
  }
  const float ig = 1.f / (1.f + expf(-gi));
  const float fg = 1.f / (1.f + expf(-gf));
  const float g2 = tanhf(gg);
  const float og = 1.f / (1.f + expf(-go));
  const float c = fg * c_f[idx] + ig * g2;
  c_f[idx] = c;
  const float h = og * tanhf(c);
  h_f[idx] = h;
  u16 a, b, cc; split3(h, a, b, cc);
  const int o = m * KX + E_ + u;
  xh_h[o] = a; xh_m[o] = b; xh_l[o] = cc;
}

// logits: [128 x 1024](h_hi) * w_out_hi^T -> out[t].  grid 250 x 256thr.
// block tile 128x128; wave = 128m x 32n; A via LDS (pad 72), B direct global.
__global__ __launch_bounds__(256) void k_logits(
    const u16* __restrict__ xh_h, const u16* __restrict__ wo,
    const float* __restrict__ bout, float* __restrict__ out, int t){
  __shared__ alignas(16) u16 lA[128 * 72];
  const int tid = threadIdx.x;
  const int L = tid & 63, wv = tid >> 6;
  const int l15 = L & 15, q = L >> 4;
  const int C0 = blockIdx.x * 128;

  f32x4 acc[8][2];
  const f32x4 z4 = {0.f, 0.f, 0.f, 0.f};
#pragma unroll
  for (int i = 0; i < 8; ++i){ acc[i][0] = z4; acc[i][1] = z4; }

  const u16* bptr0 = wo + (size_t)(C0 + wv * 32 + l15) * H_ + q * 8;
  const u16* bptr1 = bptr0 + (size_t)16 * H_;

#pragma unroll 1
  for (int it = 0; it < 16; ++it){
    const int k0 = it * 64;
#pragma unroll
    for (int s2 = 0; s2 < 4; ++s2){
      const int c = tid + 256 * s2;       // 0..1023 : 128 rows x 8 chunks
      const int row = c >> 3, ch = c & 7;
      *reinterpret_cast<uint4*>(&lA[row * 72 + ch * 8]) =
        *reinterpret_cast<const uint4*>(&xh_h[(size_t)row * KX + E_ + k0 + ch * 8]);
    }
    __syncthreads();
    const bf16x8 b00 = ldb8(bptr0 + k0);
    const bf16x8 b01 = ldb8(bptr0 + k0 + 32);
    const bf16x8 b10 = ldb8(bptr1 + k0);
    const bf16x8 b11 = ldb8(bptr1 + k0 + 32);
#pragma unroll
    for (int i = 0; i < 8; ++i){
      const bf16x8 a0 = ldb8(&lA[(i * 16 + l15) * 72 + q * 8]);
      const bf16x8 a1 = ldb8(&lA[(i * 16 + l15) * 72 + 32 + q * 8]);
      acc[i][0] = mf(a0, b00, acc[i][0]);
      acc[i][0] = mf(a1, b01, acc[i][0]);
      acc[i][1] = mf(a0, b10, acc[i][1]);
      acc[i][1] = mf(a1, b11, acc[i][1]);
    }
    __syncthreads();
  }
  const size_t ob = (size_t)t * B_ * V_;
#pragma unroll
  for (int j = 0; j < 2; ++j){
    const int n = C0 + wv * 32 + j * 16 + l15;
    const float bo = bout[n];
#pragma unroll
    for (int i = 0; i < 8; ++i)
#pragma unroll
      for (int r = 0; r < 4; ++r){
        const int m = i * 16 + q * 4 + r;
        out[ob + (size_t)m * V_ + n] = acc[i][j][r] + bo;
      }
  }
}

// per-row argmax with fp64 refinement of top-8, then embedding gather + split.
// grid 128 (one block per batch row) x 256thr.
__global__ __launch_bounds__(256) void k_argmax(
    const float* __restrict__ out, int t,
    const float* __restrict__ h_f, const float* __restrict__ w_out,
    const float* __restrict__ bout, const float* __restrict__ emb,
    u16* __restrict__ xh_h, u16* __restrict__ xh_m, u16* __restrict__ xh_l){
  __shared__ float cv[512];
  __shared__ int   ci[512];
  __shared__ int   sel_i[8];
  __shared__ double refv[8];
  __shared__ int   s_tok;
  const int m = blockIdx.x, tid = threadIdx.x;
  const float* row = out + (size_t)t * B_ * V_ + (size_t)m * V_;

  // per-thread top-2 over strided slice (125 elems)
  float v1 = -1e38f, v2 = -1e38f; int i1 = 0, i2 = 0;
  for (int n = tid; n < V_; n += 256){
    const float v = row[n];
    if (v > v1){ v2 = v1; i2 = i1; v1 = v; i1 = n; }
    else if (v > v2){ v2 = v; i2 = n; }
  }
  cv[tid] = v1; ci[tid] = i1; cv[256 + tid] = v2; ci[256 + tid] = i2;
  __syncthreads();

  // wave 0 extracts top-8 of the 512 candidates
  for (int s = 0; s < 8; ++s){
    if (tid < 64){
      float bv = -1e38f; int bp = 0;
#pragma unroll
      for (int qq = 0; qq < 8; ++qq){
        const int p = tid * 8 + qq;
        const float v = cv[p];
        if (v > bv){ bv = v; bp = p; }
      }
      for (int off = 32; off >= 1; off >>= 1){
        const float ov = __shfl_xor(bv, off);
        const int   op = __shfl_xor(bp, off);
        if (ov > bv || (ov == bv && op < bp)){ bv = ov; bp = op; }
      }
      if (tid == 0) sel_i[s] = ci[bp];
      if ((bp >> 3) == tid) cv[bp] = -1e38f;
    }
    __syncthreads();
  }

  // fp64 re-score of the 8 candidates: 32 lanes per candidate
  {
    const int wv = tid >> 6, L = tid & 63;
    const int c = wv * 2 + (L >> 5);
    const int kk = L & 31;
    const int idx = sel_i[c];
    const float* hr = h_f + (size_t)m * H_;
    const float* wr = w_out + (size_t)idx * H_;
    double a = 0.0;
#pragma unroll 4
    for (int qq = 0; qq < 32; ++qq){
      const int k = qq * 32 + kk;
      a += (double)hr[k] * (double)wr[k];
    }
    for (int off = 16; off >= 1; off >>= 1) a += __shfl_xor(a, off);
    if (kk == 0) refv[c] = a + (double)bout[idx];
  }
  __syncthreads();

  if (tid == 0){
    double bb = -1e300; int bi = 0x7fffffff;
#pragma unroll
    for (int c = 0; c < 8; ++c){
      const double v = refv[c]; const int idx = sel_i[c];
      if (v > bb || (v == bb && idx < bi)){ bb = v; bi = idx; }
    }
    s_tok = bi;
  }
  __syncthreads();

  const int tok = s_tok;
  for (int k = tid; k < E_; k += 256){
    const float v = emb[(size_t)tok * E_ + k];
    u16 a, b, c2; split3(v, a, b, c2);
    const int o = m * KX + k;
    xh_h[o] = a; xh_m[o] = b; xh_l[o] = c2;
  }
}

// ---------------- host ----------------

extern "C" void kernel_launch(void* const* d_in, const int* in_sizes, int n_in,
                              void* d_out, int out_size, void* d_ws, size_t ws_size,
                              hipStream_t stream){
  const float* enc_h = (const float*)d_in[0];
  const float* enc_c = (const float*)d_in[1];
  const float* emb   = (const float*)d_in[2];
  const float* w_ih  = (const float*)d_in[3];
  const float* w_hh  = (const float*)d_in[4];
  const float* b_ih  = (const float*)d_in[5];
  const float* b_hh  = (const float*)d_in[6];
  const float* w_out = (const float*)d_in[7];
  const float* b_out = (const float*)d_in[8];
  const int*   sos   = (const int*)d_in[9];
  float* out = (float*)d_out;

  // workspace carve (~108.6 MB)
  char* ws = (char*)d_ws;
  const size_t XH_SZ = (size_t)B_ * KX * 2;
  const size_t WC_SZ = (size_t)G4 * KX * 2;
  const size_t WO_SZ = (size_t)V_ * H_ * 2;
  const size_t PT_SZ = (size_t)4 * B_ * G4 * 4;
  const size_t HC_SZ = (size_t)B_ * H_ * 4;
  u16* xh_h = (u16*)ws; ws += XH_SZ;
  u16* xh_m = (u16*)ws; ws += XH_SZ;
  u16* xh_l = (u16*)ws; ws += XH_SZ;
  u16* wc_h = (u16*)ws; ws += WC_SZ;
  u16* wc_m = (u16*)ws; ws += WC_SZ;
  u16* wc_l = (u16*)ws; ws += WC_SZ;
  u16* wo   = (u16*)ws; ws += WO_SZ;
  float* part = (float*)ws; ws += PT_SZ;
  float* h_f  = (float*)ws; ws += HC_SZ;
  float* c_f  = (float*)ws; ws += HC_SZ;

  k_zero<<<4000, 256, 0, stream>>>(out);
  k_wout<<<32000, 256, 0, stream>>>(w_out, wo);
  k_wc<<<dim3(6, 4096), 256, 0, stream>>>(w_ih, w_hh, wc_h, wc_m, wc_l);
  k_xh0<<<dim3(6, 128), 256, 0, stream>>>(emb, enc_h, sos, xh_h, xh_m, xh_l);
  k_c0<<<512, 256, 0, stream>>>(enc_c, c_f);

  for (int t = 1; t < 48; ++t){
    k_gates<<<512, 64, 0, stream>>>(xh_h, xh_m, xh_l, wc_h, wc_m, wc_l, part);
    k_cell<<<512, 256, 0, stream>>>(part, b_ih, b_hh, c_f, h_f, xh_h, xh_m, xh_l);
    k_logits<<<250, 256, 0, stream>>>(xh_h, wo, b_out, out, t);
    if (t < 47)
      k_argmax<<<128, 256, 0, stream>>>(out, t, h_f, w_out, b_out, emb,
                                        xh_h, xh_m, xh_l);
  }
}